// Round 14
// baseline (42.894 us; speedup 1.0000x reference)
//
#include <hip/hip_runtime.h>
#include <stdint.h>
#include <limits.h>

// ---------------------------------------------------------------------------
// GeToInformedNeighborSampler — round 14 (r12 base + int4 gather).
//
// Exact clip-aware reduction (validated rounds 5-12, absmax 0):
//   A = max_{j<D} v_j, a = first argmax   (v_j = gumbel(s*NC+j) + logp[j])
//   r[s] = (exists j in [D,NC): v_j > A) ? D-1 : a
//
// Round-13 lesson: cooperative launch + grid.sync hangs under the harness's
// graph capture (600s timeout). Software grid barriers are also out (r7:
// same-line device-scope RMWs ~50cy serialized => 2048-block barrier ~20-40us,
// and deadlock risk if co-residency assumption breaks). Timed path = plain
// kernel nodes only. Structure stays r12's 3 nodes:
//   1. phasea_kernel  — per-sample first-argmax over j<D + zero padded flag
//   2. witness_kernel — per-wave windows, lane-parallel candidate eval,
//                       poll-abort on private 256B flag line, gated store
//   3. gather_kernel  — select folded in; NOW int4-vectorized: 4 output
//                       elements/thread, one dwordx4 store per half, one
//                       division per thread, (b,s) advanced incrementally
//                       (statically unrolled — no runtime-indexed arrays).
//
// RNG (threefry2x32 key (0,42), classic split, o0-only) + raw-bits prune
// filter kb(A) + flag discipline: unchanged (absmax 0, 11 straight rounds).
// All cross-kernel handoffs AGENT-scope (G16).
// ---------------------------------------------------------------------------

#define DEVI __device__ __forceinline__

DEVI uint32_t rotl32(uint32_t x, int n) { return (x << n) | (x >> (32 - n)); }

// threefry2x32-20, key (0,42), o0 only. x1 must already include +K1 (=42).
DEVI uint32_t tf_o0p(uint32_t x0, uint32_t x1) {
  const uint32_t K1 = 42u;
  const uint32_t K2 = 0x1BD11BDAu ^ K1;  // K0 = 0
#define TFR(r) x0 += x1; x1 = rotl32(x1, (r)); x1 ^= x0;
  TFR(13) TFR(15) TFR(26) TFR(6)
  x0 += K1; x1 += K2 + 1u;
  TFR(17) TFR(29) TFR(16) TFR(24)
  x0 += K2; x1 += 2u;                    // + K0 + 2
  TFR(13) TFR(15) TFR(26) TFR(6)
  /* x0 += K0 */ x1 += K1 + 3u;
  TFR(17) TFR(29) TFR(16) TFR(24)
  x0 += K1; x1 += K2 + 4u;
  TFR(13) TFR(15) TFR(26)
  x0 += x1;                              // round 20: only the add feeds o0
  x0 += K2;                              // final injection for o0
#undef TFR
  return x0;
}

DEVI uint32_t ld_dev_u32(const uint32_t* p) {
  return __hip_atomic_load(p, __ATOMIC_RELAXED, __HIP_MEMORY_SCOPE_AGENT);
}
DEVI void st_dev_u32(uint32_t* p, uint32_t v) {
  __hip_atomic_store(p, v, __ATOMIC_RELAXED, __HIP_MEMORY_SCOPE_AGENT);
}

// Raw-bits prune threshold: all j with g_j > m satisfy bits >= kb(m).
DEVI uint32_t prune_kb(float m) {
  float t = expf(-expf(-m)) - 1e-5f;
  if (!(t > 0.0f)) return 0u;
  uint32_t k = (uint32_t)ceilf(t * 8388608.0f);
  if (k > 8388607u) k = 8388607u;
  return k << 9;
}

// Exact JAX gumbel+logit value of element j of one sample.
DEVI float eval_v(uint32_t bits, uint32_t j,
                  const int* __restrict__ ids, const int* __restrict__ geto,
                  const float* __restrict__ probs, int D, int dlog) {
  float u = __uint_as_float((bits >> 9) | 0x3f800000u) - 1.0f;
  u = fmaxf(u, 1.17549435e-38f);
  float g = -logf(-logf(u));
  uint32_t b, d;
  if (dlog >= 0) { b = j >> dlog; d = j & (uint32_t)(D - 1); }
  else { b = j / (uint32_t)D; d = j - b * (uint32_t)D; }
  float lp = logf(probs[geto[(uint32_t)ids[b] * (uint32_t)D + d]]);
  return g + lp;
}

// In-wave phase A: returns A and first-argmax ai to all lanes.
DEVI void phase_a(const int* __restrict__ ids, const int* __restrict__ geto,
                  const float* __restrict__ probs,
                  uint32_t sbase, int D, int dlog, uint32_t dcK, int lane,
                  float& A, int& ai) {
  float av = -INFINITY;
  int aix = INT_MAX;
  for (uint32_t j = (uint32_t)lane; j < (uint32_t)D; j += 64u) {
    uint32_t cc = sbase + j;
    float v = eval_v(tf_o0p(cc, cc + dcK), j, ids, geto, probs, D, dlog);
    if (v > av) { av = v; aix = (int)j; }   // ascending j: > keeps first
  }
  for (int off = 32; off > 0; off >>= 1) {
    float v2 = __shfl_xor(av, off);
    int i2 = __shfl_xor(aix, off);
    if (v2 > av || (v2 == av && i2 < aix)) { av = v2; aix = i2; }
  }
  A = av; ai = aix;
}

// ---- K1: tiny phase-A writer + flag zero ----------------------------------
__global__ __launch_bounds__(64) void phasea_kernel(
    const int* __restrict__ ids, const int* __restrict__ geto,
    const float* __restrict__ probs,
    uint32_t* __restrict__ aidx, uint32_t* __restrict__ wflag,
    int NC, int D, int dlog, uint32_t dcK) {
  const int s = blockIdx.x;
  const uint32_t sbase = (uint32_t)s * (uint32_t)NC;
  float A; int ai;
  phase_a(ids, geto, probs, sbase, D, dlog, dcK, threadIdx.x, A, ai);
  if (threadIdx.x == 0) {
    st_dev_u32(&aidx[s], (uint32_t)ai);
    st_dev_u32(&wflag[s * 64], 0u);      // private 256B line, zeroed each call
  }
}

// ---- K2: witness scan, lane-parallel candidate evaluation -----------------
__global__ __launch_bounds__(256) void witness_kernel(
    const int* __restrict__ ids, const int* __restrict__ geto,
    const float* __restrict__ probs, uint32_t* __restrict__ wflag,
    int NC, int D, int dlog, uint32_t dcK, int wwin, int WV) {
  const int s = blockIdx.y;
  const int wv = blockIdx.x * 4 + (threadIdx.x >> 6);   // wave-window id
  const int lane = threadIdx.x & 63;
  if (wv >= WV) return;
  const uint32_t sbase = (uint32_t)s * (uint32_t)NC;
  uint32_t* flagp = &wflag[s * 64];

  // Phase A recomputed in-wave (no cross-kernel A/kb handoff).
  float A; int ai_unused;
  phase_a(ids, geto, probs, sbase, D, dlog, dcK, lane, A, ai_unused);
  const uint32_t kb = prune_kb(A);

  uint32_t wstart = (uint32_t)D + (uint32_t)wv * (uint32_t)wwin;
  uint32_t wend = wstart + (uint32_t)wwin;
  if (wend > (uint32_t)NC) wend = (uint32_t)NC;

  for (uint32_t base = wstart; base < wend; base += 512u) {
    // Poll issued early (independent load), consumed at round end.
    uint32_t poll = 0u;
    if (lane == 0) poll = ld_dev_u32(flagp);

    // Hash 8 chains; build per-lane pass mask only (no stored hash array).
    uint32_t pm = 0u;
#pragma unroll
    for (int c = 0; c < 8; ++c) {
      uint32_t j = base + (uint32_t)(c * 64) + (uint32_t)lane;
      uint32_t cc = sbase + j;
      uint32_t bits = tf_o0p(cc, cc + dcK);
      if (bits >= kb && j < wend) pm |= (1u << c);
    }

    bool found = false;
    if (__any(pm != 0u)) {
      // Ballot passers per chain slot; assign ordinals to lanes.
      unsigned long long bal0 = __ballot((pm >> 0) & 1u);
      unsigned long long bal1 = __ballot((pm >> 1) & 1u);
      unsigned long long bal2 = __ballot((pm >> 2) & 1u);
      unsigned long long bal3 = __ballot((pm >> 3) & 1u);
      unsigned long long bal4 = __ballot((pm >> 4) & 1u);
      unsigned long long bal5 = __ballot((pm >> 5) & 1u);
      unsigned long long bal6 = __ballot((pm >> 6) & 1u);
      unsigned long long bal7 = __ballot((pm >> 7) & 1u);
      int c0 = __popcll(bal0), c1 = __popcll(bal1), c2 = __popcll(bal2),
          c3 = __popcll(bal3), c4 = __popcll(bal4), c5 = __popcll(bal5),
          c6 = __popcll(bal6);
      int b1 = c0, b2 = b1 + c1, b3 = b2 + c2, b4 = b3 + c3,
          b5 = b4 + c4, b6 = b5 + c5, b7 = b6 + c6, tot = b7 + __popcll(bal7);

      for (int ord0 = 0; ord0 < tot && !found; ord0 += 64) {
        int myord = ord0 + lane;
        float v = -INFINITY;
        if (myord < tot) {
          int myc = 7, rank = myord - b7;
          unsigned long long m = bal7;
          if (myord < b1) { myc = 0; rank = myord;      m = bal0; }
          else if (myord < b2) { myc = 1; rank = myord - b1; m = bal1; }
          else if (myord < b3) { myc = 2; rank = myord - b2; m = bal2; }
          else if (myord < b4) { myc = 3; rank = myord - b3; m = bal3; }
          else if (myord < b5) { myc = 4; rank = myord - b4; m = bal4; }
          else if (myord < b6) { myc = 5; rank = myord - b5; m = bal5; }
          else if (myord < b7) { myc = 6; rank = myord - b6; m = bal6; }
          for (int i = 0; i < rank; ++i) m &= m - 1;   // rank-th set bit
          int src = __ffsll((unsigned long long)m) - 1;
          uint32_t j = base + (uint32_t)(myc * 64) + (uint32_t)src;
          uint32_t cc = sbase + j;
          v = eval_v(tf_o0p(cc, cc + dcK), j, ids, geto, probs, D, dlog);
        }
        if (__any(v > A)) found = true;   // all candidate chains in flight
      }
    }

    uint32_t p0 = (uint32_t)__shfl((int)poll, 0);
    if (found) {
      // plain agent store, gated: p0==1 => flag already 1 (monotonic), skip.
      if (lane == 0 && p0 == 0u) st_dev_u32(flagp, 1u);
      return;
    }
    if (p0) return;                      // someone else already proved it
  }
}

// ---- K3: select + gather outputs (int4-vectorized, grid-stride) -----------
__global__ __launch_bounds__(256) void gather_kernel(
    const int* __restrict__ ids, const int* __restrict__ adj,
    const int* __restrict__ geto,
    const uint32_t* __restrict__ aidx, const uint32_t* __restrict__ wflag,
    int* __restrict__ out, int B, int D, int ns) {
  __shared__ int sr[64];
  if (threadIdx.x < ns) {
    int s = threadIdx.x;
    int r = ld_dev_u32(&wflag[s * 64]) ? (D - 1) : (int)ld_dev_u32(&aidx[s]);
    r = r < 0 ? 0 : (r > D - 1 ? D - 1 : r);   // take(..., mode='clip')
    sr[s] = r;
  }
  __syncthreads();
  const int total = B * ns;        // B%4==0 => total%4==0 (quad-exact)
  const int nq = total >> 2;
  const int stride = gridDim.x * blockDim.x;
  for (int q = blockIdx.x * blockDim.x + threadIdx.x; q < nq; q += stride) {
    const int t4 = q << 2;
    int b = t4 / ns;
    int s = t4 - b * ns;
    int row = ids[b] * D;
    int v0[4], v1[4];
#pragma unroll
    for (int k = 0; k < 4; ++k) {          // static unroll: no dyn reg index
      if (s == ns) { s = 0; ++b; row = ids[b] * D; }  // t4+k<total => b<B
      const int r = sr[s];
      v0[k] = adj[row + r];
      v1[k] = geto[row + r];
      ++s;
    }
    *reinterpret_cast<int4*>(out + t4) = make_int4(v0[0], v0[1], v0[2], v0[3]);
    *reinterpret_cast<int4*>(out + total + t4) =
        make_int4(v1[0], v1[1], v1[2], v1[3]);
  }
}

// Fallback scalar gather for the (never-hit here) case total % 4 != 0.
__global__ __launch_bounds__(256) void gather_kernel_scalar(
    const int* __restrict__ ids, const int* __restrict__ adj,
    const int* __restrict__ geto,
    const uint32_t* __restrict__ aidx, const uint32_t* __restrict__ wflag,
    int* __restrict__ out, int B, int D, int ns) {
  __shared__ int sr[64];
  if (threadIdx.x < ns) {
    int s = threadIdx.x;
    int r = ld_dev_u32(&wflag[s * 64]) ? (D - 1) : (int)ld_dev_u32(&aidx[s]);
    r = r < 0 ? 0 : (r > D - 1 ? D - 1 : r);
    sr[s] = r;
  }
  __syncthreads();
  int total = B * ns;
  int stride = gridDim.x * blockDim.x;
  for (int t = blockIdx.x * blockDim.x + threadIdx.x; t < total; t += stride) {
    int b = t / ns;
    int s = t - b * ns;
    int r = sr[s];
    int row = ids[b];
    out[t] = adj[row * D + r];
    out[total + t] = geto[row * D + r];
  }
}

// ---------------------------------------------------------------------------
extern "C" void kernel_launch(void* const* d_in, const int* in_sizes, int n_in,
                              void* d_out, int out_size, void* d_ws, size_t ws_size,
                              hipStream_t stream) {
  const int* ids = (const int*)d_in[0];
  const int* adj = (const int*)d_in[2];
  const int* geto = (const int*)d_in[3];
  const float* probs = (const float*)d_in[4];
  int* out = (int*)d_out;

  const int B = in_sizes[0];             // 100000
  const int D = in_sizes[2] / B;         // 64
  const int NC = B * D;                  // 6.4M categories
  const int S = D;                       // 64 total samples (RESAMPLING_RATE=0)
  int ns = out_size / (2 * B);           // 25 — only these are consumed
  if (ns > 64) ns = 64;
  const uint32_t dc = (uint32_t)(S / 2) * (uint32_t)NC;  // classic-mode half
  const uint32_t dcK = dc + 42u;         // fold +K1 into the counter offset
  const int dlog = ((D & (D - 1)) == 0) ? __builtin_ctz(D) : -1;

  // 256 wave-windows per sample; 4 waves per 256-thread block.
  const int range = NC - D;
  int wwin = (range > 0 ? (range + 255) / 256 : 512);
  wwin = (wwin + 511) & ~511;            // multiple of one 512-elem round
  const int WV = range > 0 ? (range + wwin - 1) / wwin : 0;
  const int GX = WV > 0 ? (WV + 3) / 4 : 1;

  // ws layout (u32): [aidx 64][wflag ns*64 padded lines]
  uint32_t* aidx = (uint32_t*)d_ws;
  uint32_t* wflag = aidx + 64;

  phasea_kernel<<<ns, 64, 0, stream>>>(ids, geto, probs, aidx, wflag,
                                       NC, D, dlog, dcK);
  witness_kernel<<<dim3(GX, ns), 256, 0, stream>>>(ids, geto, probs, wflag,
                                                   NC, D, dlog, dcK, wwin, WV);
  const int total = B * ns;
  if ((total & 3) == 0) {
    int nq = total >> 2;
    int gblocks = (nq + 255) / 256;
    if (gblocks > 2048) gblocks = 2048;
    gather_kernel<<<gblocks, 256, 0, stream>>>(
        ids, adj, geto, aidx, wflag, out, B, D, ns);
  } else {
    int gblocks = (total + 255) / 256;
    if (gblocks > 2048) gblocks = 2048;
    gather_kernel_scalar<<<gblocks, 256, 0, stream>>>(
        ids, adj, geto, aidx, wflag, out, B, D, ns);
  }
}

// Round 15
// 37.274 us; speedup vs baseline: 1.1508x; 1.1508x over previous
//
#include <hip/hip_runtime.h>
#include <stdint.h>
#include <limits.h>

// ---------------------------------------------------------------------------
// GeToInformedNeighborSampler — round 15 (cut witness per-wave fixed cost).
//
// Exact clip-aware reduction (validated rounds 5-14, absmax 0):
//   A = max_{j<D} v_j, a = first argmax   (v_j = gumbel(s*NC+j) + logp[j])
//   r[s] = (exists j in [D,NC): v_j > A) ? D-1 : a
//
// Round-14 attribution (via r5's clean node-overhead datum ~1.5us/node):
// witness ~ 26us, dominated by PER-WAVE FIXED WORK x 25,600 waves:
//   - in-wave phase-A recompute (~900 insts: hash + 3 logf + 2 expf) [r12
//     regression — removing the A/kb handoff was wrong at this wave count]
//   - 512-elem first round (8x64-inst hash)
// Fixes (exact semantics unchanged):
//   1. phasea writes {flag=0, A_bits, kb} on the sample's private 256B line;
//      witness loads A/kb ONCE PER BLOCK (2 agent loads + LDS broadcast,
//      3.2k loads total — 16x fewer than r9's per-wave burst).
//   2. Round size 8->4 chains (256 elems): typical waves still finish in
//      round 1 (P~0.98) at half the hash cost; straggler coverage rate
//      (elems/us over 256 waves/sample) unchanged; polls 2x more frequent.
//   3. Gather: back to r12's scalar grid-stride (int4 was neutral/worse).
//
// RNG (threefry2x32 key (0,42), classic split, o0-only), raw-bits prune
// filter kb(A), lane-parallel candidate eval, poll-abort + gated plain
// AGENT store on a private line: all unchanged (absmax 0, 12 rounds).
// All cross-kernel handoffs AGENT-scope (G16); no cooperative launch (r13).
// ---------------------------------------------------------------------------

#define DEVI __device__ __forceinline__

DEVI uint32_t rotl32(uint32_t x, int n) { return (x << n) | (x >> (32 - n)); }

// threefry2x32-20, key (0,42), o0 only. x1 must already include +K1 (=42).
DEVI uint32_t tf_o0p(uint32_t x0, uint32_t x1) {
  const uint32_t K1 = 42u;
  const uint32_t K2 = 0x1BD11BDAu ^ K1;  // K0 = 0
#define TFR(r) x0 += x1; x1 = rotl32(x1, (r)); x1 ^= x0;
  TFR(13) TFR(15) TFR(26) TFR(6)
  x0 += K1; x1 += K2 + 1u;
  TFR(17) TFR(29) TFR(16) TFR(24)
  x0 += K2; x1 += 2u;                    // + K0 + 2
  TFR(13) TFR(15) TFR(26) TFR(6)
  /* x0 += K0 */ x1 += K1 + 3u;
  TFR(17) TFR(29) TFR(16) TFR(24)
  x0 += K1; x1 += K2 + 4u;
  TFR(13) TFR(15) TFR(26)
  x0 += x1;                              // round 20: only the add feeds o0
  x0 += K2;                              // final injection for o0
#undef TFR
  return x0;
}

DEVI uint32_t ld_dev_u32(const uint32_t* p) {
  return __hip_atomic_load(p, __ATOMIC_RELAXED, __HIP_MEMORY_SCOPE_AGENT);
}
DEVI void st_dev_u32(uint32_t* p, uint32_t v) {
  __hip_atomic_store(p, v, __ATOMIC_RELAXED, __HIP_MEMORY_SCOPE_AGENT);
}

// Raw-bits prune threshold: all j with g_j > m satisfy bits >= kb(m).
DEVI uint32_t prune_kb(float m) {
  float t = expf(-expf(-m)) - 1e-5f;
  if (!(t > 0.0f)) return 0u;
  uint32_t k = (uint32_t)ceilf(t * 8388608.0f);
  if (k > 8388607u) k = 8388607u;
  return k << 9;
}

// Exact JAX gumbel+logit value of element j of one sample.
DEVI float eval_v(uint32_t bits, uint32_t j,
                  const int* __restrict__ ids, const int* __restrict__ geto,
                  const float* __restrict__ probs, int D, int dlog) {
  float u = __uint_as_float((bits >> 9) | 0x3f800000u) - 1.0f;
  u = fmaxf(u, 1.17549435e-38f);
  float g = -logf(-logf(u));
  uint32_t b, d;
  if (dlog >= 0) { b = j >> dlog; d = j & (uint32_t)(D - 1); }
  else { b = j / (uint32_t)D; d = j - b * (uint32_t)D; }
  float lp = logf(probs[geto[(uint32_t)ids[b] * (uint32_t)D + d]]);
  return g + lp;
}

// In-wave phase A: returns A and first-argmax ai to all lanes.
DEVI void phase_a(const int* __restrict__ ids, const int* __restrict__ geto,
                  const float* __restrict__ probs,
                  uint32_t sbase, int D, int dlog, uint32_t dcK, int lane,
                  float& A, int& ai) {
  float av = -INFINITY;
  int aix = INT_MAX;
  for (uint32_t j = (uint32_t)lane; j < (uint32_t)D; j += 64u) {
    uint32_t cc = sbase + j;
    float v = eval_v(tf_o0p(cc, cc + dcK), j, ids, geto, probs, D, dlog);
    if (v > av) { av = v; aix = (int)j; }   // ascending j: > keeps first
  }
  for (int off = 32; off > 0; off >>= 1) {
    float v2 = __shfl_xor(av, off);
    int i2 = __shfl_xor(aix, off);
    if (v2 > av || (v2 == av && i2 < aix)) { av = v2; aix = i2; }
  }
  A = av; ai = aix;
}

// ---- K1: phase A writer + {flag, A, kb} line init -------------------------
__global__ __launch_bounds__(64) void phasea_kernel(
    const int* __restrict__ ids, const int* __restrict__ geto,
    const float* __restrict__ probs,
    uint32_t* __restrict__ aidx, uint32_t* __restrict__ wline,
    int NC, int D, int dlog, uint32_t dcK) {
  const int s = blockIdx.x;
  const uint32_t sbase = (uint32_t)s * (uint32_t)NC;
  float A; int ai;
  phase_a(ids, geto, probs, sbase, D, dlog, dcK, threadIdx.x, A, ai);
  if (threadIdx.x == 0) {
    st_dev_u32(&aidx[s], (uint32_t)ai);
    uint32_t* line = &wline[s * 64];     // private 256B line per sample
    st_dev_u32(&line[1], __float_as_uint(A));
    st_dev_u32(&line[2], prune_kb(A));
    st_dev_u32(&line[0], 0u);            // flag zeroed every call
  }
}

// ---- K2: witness scan — 4-chain rounds, per-block A/kb broadcast ----------
__global__ __launch_bounds__(256) void witness_kernel(
    const int* __restrict__ ids, const int* __restrict__ geto,
    const float* __restrict__ probs, uint32_t* __restrict__ wline,
    int NC, int D, int dlog, uint32_t dcK, int wwin, int WV) {
  const int s = blockIdx.y;
  const int wv = blockIdx.x * 4 + (threadIdx.x >> 6);   // wave-window id
  const int lane = threadIdx.x & 63;
  const uint32_t sbase = (uint32_t)s * (uint32_t)NC;
  uint32_t* line = &wline[s * 64];

  // Per-BLOCK load of A/kb (written by phasea), LDS broadcast.
  __shared__ uint32_t sAb, skb;
  if (threadIdx.x == 0) {
    sAb = ld_dev_u32(&line[1]);
    skb = ld_dev_u32(&line[2]);
  }
  __syncthreads();
  const float A = __uint_as_float(sAb);
  const uint32_t kb = skb;

  if (wv >= WV) return;
  uint32_t wstart = (uint32_t)D + (uint32_t)wv * (uint32_t)wwin;
  uint32_t wend = wstart + (uint32_t)wwin;
  if (wend > (uint32_t)NC) wend = (uint32_t)NC;

  for (uint32_t base = wstart; base < wend; base += 256u) {
    // Poll issued early (independent load), consumed at round end.
    uint32_t poll = 0u;
    if (lane == 0) poll = ld_dev_u32(line);

    // Hash 4 chains; per-lane pass mask.
    uint32_t pm = 0u;
#pragma unroll
    for (int c = 0; c < 4; ++c) {
      uint32_t j = base + (uint32_t)(c * 64) + (uint32_t)lane;
      uint32_t cc = sbase + j;
      uint32_t bits = tf_o0p(cc, cc + dcK);
      if (bits >= kb && j < wend) pm |= (1u << c);
    }

    bool found = false;
    if (__any(pm != 0u)) {
      // Ballot passers per chain slot; assign ordinals to lanes.
      unsigned long long bal0 = __ballot((pm >> 0) & 1u);
      unsigned long long bal1 = __ballot((pm >> 1) & 1u);
      unsigned long long bal2 = __ballot((pm >> 2) & 1u);
      unsigned long long bal3 = __ballot((pm >> 3) & 1u);
      int c0 = __popcll(bal0), c1 = __popcll(bal1), c2 = __popcll(bal2);
      int b1 = c0, b2 = b1 + c1, b3 = b2 + c2, tot = b3 + __popcll(bal3);

      for (int ord0 = 0; ord0 < tot && !found; ord0 += 64) {
        int myord = ord0 + lane;
        float v = -INFINITY;
        if (myord < tot) {
          int myc = 3, rank = myord - b3;
          unsigned long long m = bal3;
          if (myord < b1) { myc = 0; rank = myord;      m = bal0; }
          else if (myord < b2) { myc = 1; rank = myord - b1; m = bal1; }
          else if (myord < b3) { myc = 2; rank = myord - b2; m = bal2; }
          for (int i = 0; i < rank; ++i) m &= m - 1;   // rank-th set bit
          int src = __ffsll((unsigned long long)m) - 1;
          uint32_t j = base + (uint32_t)(myc * 64) + (uint32_t)src;
          uint32_t cc = sbase + j;
          v = eval_v(tf_o0p(cc, cc + dcK), j, ids, geto, probs, D, dlog);
        }
        if (__any(v > A)) found = true;   // all candidate chains in flight
      }
    }

    uint32_t p0 = (uint32_t)__shfl((int)poll, 0);
    if (found) {
      // plain agent store, gated: p0==1 => flag already 1 (monotonic), skip.
      if (lane == 0 && p0 == 0u) st_dev_u32(line, 1u);
      return;
    }
    if (p0) return;                      // someone else already proved it
  }
}

// ---- K3: select + gather outputs (scalar grid-stride, r12-proven) ---------
__global__ __launch_bounds__(256) void gather_kernel(
    const int* __restrict__ ids, const int* __restrict__ adj,
    const int* __restrict__ geto,
    const uint32_t* __restrict__ aidx, const uint32_t* __restrict__ wline,
    int* __restrict__ out, int B, int D, int ns) {
  __shared__ int sr[64];
  if (threadIdx.x < ns) {
    int s = threadIdx.x;
    int r = ld_dev_u32(&wline[s * 64]) ? (D - 1) : (int)ld_dev_u32(&aidx[s]);
    r = r < 0 ? 0 : (r > D - 1 ? D - 1 : r);   // take(..., mode='clip')
    sr[s] = r;
  }
  __syncthreads();
  int total = B * ns;
  int stride = gridDim.x * blockDim.x;
  for (int t = blockIdx.x * blockDim.x + threadIdx.x; t < total; t += stride) {
    int b = t / ns;
    int s = t - b * ns;
    int r = sr[s];
    int row = ids[b];
    out[t] = adj[row * D + r];            // weighted_adj[:, :ns]
    out[total + t] = geto[row * D + r];   // weighted_geto[:, :ns]
  }
}

// ---------------------------------------------------------------------------
extern "C" void kernel_launch(void* const* d_in, const int* in_sizes, int n_in,
                              void* d_out, int out_size, void* d_ws, size_t ws_size,
                              hipStream_t stream) {
  const int* ids = (const int*)d_in[0];
  const int* adj = (const int*)d_in[2];
  const int* geto = (const int*)d_in[3];
  const float* probs = (const float*)d_in[4];
  int* out = (int*)d_out;

  const int B = in_sizes[0];             // 100000
  const int D = in_sizes[2] / B;         // 64
  const int NC = B * D;                  // 6.4M categories
  const int S = D;                       // 64 total samples (RESAMPLING_RATE=0)
  int ns = out_size / (2 * B);           // 25 — only these are consumed
  if (ns > 64) ns = 64;
  const uint32_t dc = (uint32_t)(S / 2) * (uint32_t)NC;  // classic-mode half
  const uint32_t dcK = dc + 42u;         // fold +K1 into the counter offset
  const int dlog = ((D & (D - 1)) == 0) ? __builtin_ctz(D) : -1;

  // 256 wave-windows per sample; 4 waves per 256-thread block; 256-elem rounds.
  const int range = NC - D;
  int wwin = (range > 0 ? (range + 255) / 256 : 256);
  wwin = (wwin + 255) & ~255;            // multiple of one 256-elem round
  const int WV = range > 0 ? (range + wwin - 1) / wwin : 0;
  const int GX = WV > 0 ? (WV + 3) / 4 : 1;

  // ws layout (u32): [aidx 64][wline ns*64 padded lines: {flag, A, kb}]
  uint32_t* aidx = (uint32_t*)d_ws;
  uint32_t* wline = aidx + 64;

  phasea_kernel<<<ns, 64, 0, stream>>>(ids, geto, probs, aidx, wline,
                                       NC, D, dlog, dcK);
  witness_kernel<<<dim3(GX, ns), 256, 0, stream>>>(ids, geto, probs, wline,
                                                   NC, D, dlog, dcK, wwin, WV);
  int total = B * ns;
  int gblocks = (total + 255) / 256;
  if (gblocks > 2048) gblocks = 2048;
  gather_kernel<<<gblocks, 256, 0, stream>>>(
      ids, adj, geto, aidx, wline, out, B, D, ns);
}